// Round 1
// baseline (28470.648 us; speedup 1.0000x reference)
//
#include <hip/hip_runtime.h>
#include <math.h>

#pragma clang fp contract(off)

#define BB 32
#define CC 64
#define LL 8192
#define NW 1021      // number of spectral windows: (8192-32)/8 + 1
#define MAXSEG 1024
#define MAXTOK 1024
#define BNDCAP 1026

// ---------------------------------------------------------------------------
// numpy pairwise_sum replica (loops.c.src): n<8 sequential, n<=128 blocked with
// 8 accumulators, else recursive halving with n2 -= n2 % 8.
// ---------------------------------------------------------------------------
template <typename F>
__device__ double np_pairwise(const F& f, int off, int n) {
  if (n < 8) {
    double res = 0.0;
    for (int i = 0; i < n; i++) res = res + f(off + i);
    return res;
  }
  if (n <= 128) {
    double r0 = f(off + 0), r1 = f(off + 1), r2 = f(off + 2), r3 = f(off + 3);
    double r4 = f(off + 4), r5 = f(off + 5), r6 = f(off + 6), r7 = f(off + 7);
    int i = 8;
    int lim = n - (n % 8);
    for (; i < lim; i += 8) {
      r0 = r0 + f(off + i + 0); r1 = r1 + f(off + i + 1);
      r2 = r2 + f(off + i + 2); r3 = r3 + f(off + i + 3);
      r4 = r4 + f(off + i + 4); r5 = r5 + f(off + i + 5);
      r6 = r6 + f(off + i + 6); r7 = r7 + f(off + i + 7);
    }
    double res = ((r0 + r1) + (r2 + r3)) + ((r4 + r5) + (r6 + r7));
    for (; i < n; i++) res = res + f(off + i);
    return res;
  }
  int n2 = n / 2;
  n2 -= n2 % 8;
  return np_pairwise(f, off, n2) + np_pairwise(f, off + n2, n - n2);
}

// ---------------------------------------------------------------------------
// Stage 1: agg[b][l] = mean over channels, replicating numpy's sequential f32
// row-accumulation order (axis-0 reduce), then /64 (exact), then cast f64.
// ---------------------------------------------------------------------------
__global__ void k_agg(const float* __restrict__ x, double* __restrict__ agg) {
  int idx = blockIdx.x * blockDim.x + threadIdx.x;
  if (idx >= BB * LL) return;
  int b = idx / LL, l = idx - b * LL;
  const float* xb = x + (size_t)b * CC * LL + l;
  float s = 0.0f;
  for (int c = 0; c < CC; c++) s = s + xb[(size_t)c * LL];
  agg[idx] = (double)(s / 64.0f);
}

// ---------------------------------------------------------------------------
// Stage 2: per-window spectral features. 32-point real DFT, bins 1..16,
// feat = [dom/32, bw, log1p(mean power)] with numpy's 16-elem blocked sums.
// ---------------------------------------------------------------------------
__global__ void k_winfeat(const double* __restrict__ agg, double* __restrict__ feat) {
  __shared__ double tc[32], tsn[32];
  if (threadIdx.x < 32) {
    double th = 6.283185307179586 * ((double)threadIdx.x / 32.0);
    tc[threadIdx.x] = cos(th);
    tsn[threadIdx.x] = sin(th);
  }
  __syncthreads();
  int idx = blockIdx.x * blockDim.x + threadIdx.x;
  if (idx >= BB * NW) return;
  int b = idx / NW, w = idx - b * NW;
  const double* a = agg + (size_t)b * LL + (size_t)w * 8;
  double av[32];
#pragma unroll
  for (int t = 0; t < 32; t++) av[t] = a[t];
  double p[16];
  for (int k = 1; k <= 16; k++) {
    double re = 0.0, im = 0.0;
    int m = 0;
    for (int t = 0; t < 32; t++) {
      re = re + av[t] * tc[m];
      im = im + av[t] * tsn[m];
      m = (m + k) & 31;
    }
    p[k - 1] = re * re + im * im;
  }
  double r[8];
  for (int i = 0; i < 8; i++) r[i] = p[i] + p[i + 8];
  double sum = ((r[0] + r[1]) + (r[2] + r[3])) + ((r[4] + r[5]) + (r[6] + r[7]));
  double tot = (sum > 1e-8) ? sum : 1e-8;
  double pf[16];
  for (int i = 0; i < 16; i++) pf[i] = p[i] * (double)(i + 1);
  for (int i = 0; i < 8; i++) r[i] = pf[i] + pf[i + 8];
  double spf = ((r[0] + r[1]) + (r[2] + r[3])) + ((r[4] + r[5]) + (r[6] + r[7]));
  int dom = 0;
  double bv = p[0];
  for (int i = 1; i < 16; i++)
    if (p[i] > bv) { bv = p[i]; dom = i; }
  dom += 1;
  double cent = spf / tot;
  double q[16];
  for (int i = 0; i < 16; i++) {
    double d = (double)(i + 1) - cent;
    double dd = d * d;
    q[i] = dd * p[i];
  }
  for (int i = 0; i < 8; i++) r[i] = q[i] + q[i + 8];
  double sv = ((r[0] + r[1]) + (r[2] + r[3])) + ((r[4] + r[5]) + (r[6] + r[7]));
  double var = sv / tot;
  double bw = sqrt(var > 0.0 ? var : 0.0) / 32.0;
  double mean = sum / 16.0;
  double* f = feat + ((size_t)b * NW + (size_t)w) * 3;
  f[0] = (double)dom / 32.0;
  f[1] = bw;
  f[2] = log1p(mean);
}

// ---------------------------------------------------------------------------
// Stage 3: PELT DP per batch. One 1024-thread block per batch; thread j holds
// pre[j]/pre2[j]/dp[j] in registers; two barriers per step for lex-min argmin.
// Thread 0 then backtracks and applies the boundary filter.
// ---------------------------------------------------------------------------
__global__ __launch_bounds__(1024) void k_dp(const double* __restrict__ feat,
                                             int* __restrict__ bnd_g,
                                             int* __restrict__ nbnd_g) {
  __shared__ double preL[(NW + 1) * 3];
  __shared__ double pre2L[(NW + 1) * 3];
  __shared__ int prevL[NW + 1];
  __shared__ double pvals[16];
  __shared__ int pidx[16];
  __shared__ double bval;
  int b = blockIdx.x;
  int j = threadIdx.x;
  const double* fb = feat + (size_t)b * NW * 3;
  if (j == 0) {
    double c0 = 0, c1 = 0, c2 = 0, d0 = 0, d1 = 0, d2 = 0;
    preL[0] = 0; preL[1] = 0; preL[2] = 0;
    pre2L[0] = 0; pre2L[1] = 0; pre2L[2] = 0;
    for (int i = 0; i < NW; i++) {
      double f0 = fb[i * 3 + 0], f1 = fb[i * 3 + 1], f2 = fb[i * 3 + 2];
      c0 = c0 + f0; c1 = c1 + f1; c2 = c2 + f2;
      double s0 = f0 * f0, s1 = f1 * f1, s2 = f2 * f2;
      d0 = d0 + s0; d1 = d1 + s1; d2 = d2 + s2;
      preL[(i + 1) * 3 + 0] = c0; preL[(i + 1) * 3 + 1] = c1; preL[(i + 1) * 3 + 2] = c2;
      pre2L[(i + 1) * 3 + 0] = d0; pre2L[(i + 1) * 3 + 1] = d1; pre2L[(i + 1) * 3 + 2] = d2;
    }
  }
  __syncthreads();
  double pj0 = 0, pj1 = 0, pj2 = 0, qj0 = 0, qj1 = 0, qj2 = 0;
  if (j <= NW) {
    pj0 = preL[j * 3 + 0]; pj1 = preL[j * 3 + 1]; pj2 = preL[j * 3 + 2];
    qj0 = pre2L[j * 3 + 0]; qj1 = pre2L[j * 3 + 1]; qj2 = pre2L[j * 3 + 2];
  }
  double dpj = (j == 0) ? -1.0 : 0.0;
  int lane = threadIdx.x & 63, wid = threadIdx.x >> 6;
  for (int end = 1; end <= NW; end++) {
    double pe0 = preL[end * 3 + 0], pe1 = preL[end * 3 + 1], pe2 = preL[end * 3 + 2];
    double qe0 = pre2L[end * 3 + 0], qe1 = pre2L[end * 3 + 1], qe2 = pre2L[end * 3 + 2];
    double v = __builtin_inf();
    int ix = j;
    if (j < end) {
      double sl = (double)(end - j);
      double s0 = pe0 - pj0, s1 = pe1 - pj1, s2 = pe2 - pj2;
      double u0 = s0 * s0, u1 = s1 * s1, u2 = s2 * s2;
      double t0 = (qe0 - qj0) - u0 / sl;
      double t1 = (qe1 - qj1) - u1 / sl;
      double t2 = (qe2 - qj2) - u2 / sl;
      double sse = (t0 + t1) + t2;
      v = (dpj + sse) + 1.0;
    }
#pragma unroll
    for (int o = 32; o > 0; o >>= 1) {
      double ov = __shfl_xor(v, o, 64);
      int oi = __shfl_xor(ix, o, 64);
      if (ov < v || (ov == v && oi < ix)) { v = ov; ix = oi; }
    }
    if (lane == 0) { pvals[wid] = v; pidx[wid] = ix; }
    __syncthreads();
    if (threadIdx.x == 0) {
      double mv = pvals[0];
      int mi = pidx[0];
      for (int t = 1; t < 16; t++) {
        if (pvals[t] < mv || (pvals[t] == mv && pidx[t] < mi)) { mv = pvals[t]; mi = pidx[t]; }
      }
      bval = mv;
      prevL[end] = mi;
    }
    __syncthreads();
    if (j == end) dpj = bval;
  }
  if (threadIdx.x == 0) {
    int* chain = (int*)preL;  // reuse LDS
    int cnt = 0, i = NW;
    while (i > 0) { i = prevL[i]; chain[cnt++] = i; }
    int* bb = bnd_g + (size_t)b * BNDCAP;
    int nb = 0;
    bb[nb++] = 0;
    for (int t = cnt - 2; t >= 0; t--) {  // interior breakpoints, ascending
      int w = chain[t];
      int tt = w * 8;
      if (tt <= bb[nb - 1]) continue;
      if (tt - bb[nb - 1] < 8) continue;
      if (LL - tt < 8) continue;
      bb[nb++] = tt;
    }
    bb[nb++] = LL;
    nbnd_g[b] = nb;
  }
}

// ---------------------------------------------------------------------------
// Stage 4: per-segment DFT stats + patch length. One block per batch.
// ---------------------------------------------------------------------------
__global__ __launch_bounds__(512) void k_segstats(
    const double* __restrict__ agg, const int* __restrict__ bnd_g,
    const int* __restrict__ nbnd_g, double* __restrict__ tblc,
    double* __restrict__ tbls, double* __restrict__ segp,
    int* __restrict__ seg_s, int* __restrict__ seg_e, int* __restrict__ seg_pl,
    double* __restrict__ seg_domp, double* __restrict__ seg_bw,
    int* __restrict__ nseg_g) {
  int b = blockIdx.x;
  int nb = nbnd_g[b];
  int nseg = nb - 1;
  const int* bb = bnd_g + (size_t)b * BNDCAP;
  const double* ab = agg + (size_t)b * LL;
  double* tc = tblc + (size_t)b * LL;
  double* tsn = tbls + (size_t)b * LL;
  double* pp = segp + (size_t)b * (LL / 2);
  for (int si = 0; si < nseg; si++) {
    int s = bb[si], e = bb[si + 1];
    int n = e - s;
    int nb2 = n / 2;
    for (int m = threadIdx.x; m < n; m += blockDim.x) {
      double th = 6.283185307179586 * ((double)m / (double)n);
      tc[m] = cos(th);
      tsn[m] = sin(th);
    }
    __syncthreads();
    for (int k = threadIdx.x + 1; k <= nb2; k += blockDim.x) {
      double re = 0.0, im = 0.0;
      int m = 0;
      for (int jj = 0; jj < n; jj++) {
        double av = ab[s + jj];
        re = re + av * tc[m];
        im = im + av * tsn[m];
        m += k;
        if (m >= n) m -= n;
      }
      pp[k - 1] = re * re + im * im;
    }
    __syncthreads();
    if (threadIdx.x == 0) {
      double domp, bwv;
      if (n < 2) {
        domp = 1.0; bwv = 0.0;
      } else if (nb2 <= 1) {
        domp = (double)n; bwv = 0.0;
      } else {
        double sum = np_pairwise([&](int i) { return pp[i]; }, 0, nb2);
        double tot = (sum > 1e-8) ? sum : 1e-8;
        int dom = 0;
        double bv = pp[0];
        for (int i = 1; i < nb2; i++)
          if (pp[i] > bv) { bv = pp[i]; dom = i; }
        dom += 1;
        double spf = np_pairwise([&](int i) { return pp[i] * (double)(i + 1); }, 0, nb2);
        double cent = spf / tot;
        double sv = np_pairwise(
            [&](int i) {
              double d = (double)(i + 1) - cent;
              double dd = d * d;
              return dd * pp[i];
            },
            0, nb2);
        double var = sv / tot;
        bwv = sqrt(var > 0.0 ? var : 0.0) / (double)n;
        domp = (double)n / (double)dom;
      }
      double raw = (1.0 * domp) / (1.0 + 1.0 * bwv);
      int pl = (int)rint(raw / 2.0) * 2;  // Python round = half-to-even
      if (pl < 8) pl = 8;
      if (pl > 64) pl = 64;
      seg_s[(size_t)b * MAXSEG + si] = s;
      seg_e[(size_t)b * MAXSEG + si] = e;
      seg_pl[(size_t)b * MAXSEG + si] = pl;
      seg_domp[(size_t)b * MAXSEG + si] = domp;
      seg_bw[(size_t)b * MAXSEG + si] = bwv;
    }
    __syncthreads();
  }
  if (threadIdx.x == 0) nseg_g[b] = nseg;
}

// ---------------------------------------------------------------------------
// Stage 5: token enumeration (one thread per batch) + n_tokens output.
// ---------------------------------------------------------------------------
__global__ void k_tokens(const int* __restrict__ seg_s, const int* __restrict__ seg_e,
                         const int* __restrict__ seg_pl, const int* __restrict__ nseg_g,
                         int* __restrict__ tok_a, int* __restrict__ tok_z,
                         int* __restrict__ tok_sg, int* __restrict__ ntok_g,
                         float* __restrict__ out_nt) {
  int b = blockIdx.x * blockDim.x + threadIdx.x;
  if (b >= BB) return;
  int ns = nseg_g[b];
  int cnt = 0;
  for (int si = 0; si < ns; si++) {
    int s = seg_s[(size_t)b * MAXSEG + si];
    int e = seg_e[(size_t)b * MAXSEG + si];
    int pl = seg_pl[(size_t)b * MAXSEG + si];
    for (int a = s; a < e; a += pl) {
      int z = a + pl;
      if (z > e) z = e;
      tok_a[(size_t)b * MAXTOK + cnt] = a;
      tok_z[(size_t)b * MAXTOK + cnt] = z;
      tok_sg[(size_t)b * MAXTOK + cnt] = si;
      cnt++;
    }
  }
  ntok_g[b] = cnt;
  out_nt[b] = (float)cnt;
}

// ---------------------------------------------------------------------------
// Stage 6: per-token metadata outputs (mask/start/end/center/span/regime).
// Padding stays zero from the memset.
// ---------------------------------------------------------------------------
__global__ void k_tokfill(const int* __restrict__ tok_a, const int* __restrict__ tok_z,
                          const int* __restrict__ tok_sg, const int* __restrict__ ntok_g,
                          const int* __restrict__ seg_s, const int* __restrict__ seg_e,
                          const double* __restrict__ seg_domp,
                          const double* __restrict__ seg_bw, float* __restrict__ out,
                          int mx) {
  int b = blockIdx.x;
  int t = blockIdx.y * blockDim.x + threadIdx.x;
  if (t >= mx) return;
  if (t >= ntok_g[b]) return;
  size_t BM = (size_t)BB * (size_t)mx;
  float* mask = out + BM * 1024;
  float* start = mask + BM;
  float* endo = start + BM;
  float* cen = endo + BM;
  float* span = cen + BM;
  float* reg = span + BM;
  int a = tok_a[(size_t)b * MAXTOK + t];
  int z = tok_z[(size_t)b * MAXTOK + t];
  int si = tok_sg[(size_t)b * MAXTOK + t];
  size_t o = (size_t)b * (size_t)mx + t;
  mask[o] = 1.0f;
  start[o] = (float)a;
  endo[o] = (float)z;
  cen[o] = (float)(((double)(a + z - 1) * 0.5) / 8191.0);
  span[o] = (float)((double)(z - a) / 8192.0);
  int s = seg_s[(size_t)b * MAXSEG + si];
  int e = seg_e[(size_t)b * MAXSEG + si];
  reg[o * 3 + 0] = (float)(seg_domp[(size_t)b * MAXSEG + si] / 8192.0);
  reg[o * 3 + 1] = (float)seg_bw[(size_t)b * MAXSEG + si];
  reg[o * 3 + 2] = (float)((double)(e - s) / 8192.0);
}

// ---------------------------------------------------------------------------
// Stage 7: patch gather — one block per (token, batch), 16-anchor resize plan
// in LDS, then 64 channels x 16 anchors of f32 linear interpolation.
// ---------------------------------------------------------------------------
__global__ __launch_bounds__(256) void k_patches(const float* __restrict__ x,
                                                 const int* __restrict__ tok_a,
                                                 const int* __restrict__ tok_z,
                                                 const int* __restrict__ ntok_g,
                                                 float* __restrict__ out, int mx) {
  int t = blockIdx.x, b = blockIdx.y;
  if (t >= ntok_g[b]) return;
  __shared__ int g0[16], g1[16];
  __shared__ float wS[16];
  if (threadIdx.x < 16) {
    int a = tok_a[(size_t)b * MAXTOK + t];
    int z = tok_z[(size_t)b * MAXTOK + t];
    int n = z - a;
    double src = ((double)threadIdx.x + 0.5) * ((double)n / 16.0) - 0.5;
    if (src < 0.0) src = 0.0;
    double hi = (double)n - 1.0;
    if (src > hi) src = hi;
    double fi = floor(src);
    int i0 = (int)fi;
    int i1 = i0 + 1;
    if (i1 > n - 1) i1 = n - 1;
    g0[threadIdx.x] = a + i0;
    g1[threadIdx.x] = a + i1;
    wS[threadIdx.x] = (float)(src - fi);
  }
  __syncthreads();
  const float* xb = x + (size_t)b * CC * LL;
  float* ob = out + (((size_t)b * (size_t)mx + t) * CC) * 16;
  for (int e2 = threadIdx.x; e2 < CC * 16; e2 += 256) {
    int c = e2 >> 4, ai = e2 & 15;
    float wv = wS[ai];
    float v0 = xb[(size_t)c * LL + g0[ai]];
    float v1 = xb[(size_t)c * LL + g1[ai]];
    ob[e2] = v0 * (1.0f - wv) + v1 * wv;
  }
}

extern "C" void kernel_launch(void* const* d_in, const int* in_sizes, int n_in,
                              void* d_out, int out_size, void* d_ws, size_t ws_size,
                              hipStream_t stream) {
  (void)in_sizes; (void)n_in; (void)ws_size;
  const float* x = (const float*)d_in[0];
  float* out = (float*)d_out;
  // out_size = B*(1032*mx + 1)  -> recover mx
  long mx = ((long)out_size / BB - 1) / 1032;
  if (mx < 1) mx = 1;

  char* wp = (char*)d_ws;
  size_t off = 0;
  auto carve = [&](size_t bytes) -> void* {
    void* p = wp + off;
    off += (bytes + 255) & ~(size_t)255;
    return p;
  };
  double* agg = (double*)carve((size_t)BB * LL * 8);
  double* feat = (double*)carve((size_t)BB * NW * 3 * 8);
  double* tblc = (double*)carve((size_t)BB * LL * 8);
  double* tbls = (double*)carve((size_t)BB * LL * 8);
  double* segp = (double*)carve((size_t)BB * (LL / 2) * 8);
  double* seg_domp = (double*)carve((size_t)BB * MAXSEG * 8);
  double* seg_bw = (double*)carve((size_t)BB * MAXSEG * 8);
  int* bnd = (int*)carve((size_t)BB * BNDCAP * 4);
  int* nbnd = (int*)carve((size_t)BB * 4);
  int* seg_s = (int*)carve((size_t)BB * MAXSEG * 4);
  int* seg_e = (int*)carve((size_t)BB * MAXSEG * 4);
  int* seg_pl = (int*)carve((size_t)BB * MAXSEG * 4);
  int* nseg = (int*)carve((size_t)BB * 4);
  int* tok_a = (int*)carve((size_t)BB * MAXTOK * 4);
  int* tok_z = (int*)carve((size_t)BB * MAXTOK * 4);
  int* tok_sg = (int*)carve((size_t)BB * MAXTOK * 4);
  int* ntok = (int*)carve((size_t)BB * 4);

  hipMemsetAsync(d_out, 0, (size_t)out_size * sizeof(float), stream);

  k_agg<<<(BB * LL + 255) / 256, 256, 0, stream>>>(x, agg);
  k_winfeat<<<(BB * NW + 255) / 256, 256, 0, stream>>>(agg, feat);
  k_dp<<<BB, 1024, 0, stream>>>(feat, bnd, nbnd);
  k_segstats<<<BB, 512, 0, stream>>>(agg, bnd, nbnd, tblc, tbls, segp, seg_s,
                                     seg_e, seg_pl, seg_domp, seg_bw, nseg);
  k_tokens<<<1, 64, 0, stream>>>(seg_s, seg_e, seg_pl, nseg, tok_a, tok_z,
                                 tok_sg, ntok, out + (size_t)BB * (size_t)mx * 1032);
  dim3 gf(BB, (unsigned)((mx + 255) / 256));
  k_tokfill<<<gf, 256, 0, stream>>>(tok_a, tok_z, tok_sg, ntok, seg_s, seg_e,
                                    seg_domp, seg_bw, out, (int)mx);
  dim3 gp((unsigned)mx, BB);
  k_patches<<<gp, 256, 0, stream>>>(x, tok_a, tok_z, ntok, out, (int)mx);
}

// Round 2
// 9117.310 us; speedup vs baseline: 3.1227x; 3.1227x over previous
//
#include <hip/hip_runtime.h>
#include <math.h>

#pragma clang fp contract(off)

#define BB 32
#define CC 64
#define LL 8192
#define NW 1021      // number of spectral windows: (8192-32)/8 + 1
#define MAXSEG 1024
#define MAXTOK 1024
#define BNDCAP 1026
#define NBINS (LL / 2)   // 4096 flat bins per batch (segments partition [0,L))

// ---------------------------------------------------------------------------
// numpy pairwise_sum replica (loops.c.src): n<8 sequential, n<=128 blocked with
// 8 accumulators, else recursive halving with n2 -= n2 % 8.
// ---------------------------------------------------------------------------
template <typename F>
__device__ double np_pairwise(const F& f, int off, int n) {
  if (n < 8) {
    double res = 0.0;
    for (int i = 0; i < n; i++) res = res + f(off + i);
    return res;
  }
  if (n <= 128) {
    double r0 = f(off + 0), r1 = f(off + 1), r2 = f(off + 2), r3 = f(off + 3);
    double r4 = f(off + 4), r5 = f(off + 5), r6 = f(off + 6), r7 = f(off + 7);
    int i = 8;
    int lim = n - (n % 8);
    for (; i < lim; i += 8) {
      r0 = r0 + f(off + i + 0); r1 = r1 + f(off + i + 1);
      r2 = r2 + f(off + i + 2); r3 = r3 + f(off + i + 3);
      r4 = r4 + f(off + i + 4); r5 = r5 + f(off + i + 5);
      r6 = r6 + f(off + i + 6); r7 = r7 + f(off + i + 7);
    }
    double res = ((r0 + r1) + (r2 + r3)) + ((r4 + r5) + (r6 + r7));
    for (; i < n; i++) res = res + f(off + i);
    return res;
  }
  int n2 = n / 2;
  n2 -= n2 % 8;
  return np_pairwise(f, off, n2) + np_pairwise(f, off + n2, n - n2);
}

// ---------------------------------------------------------------------------
// Stage 1: agg[b][l] = channel mean, numpy sequential f32 order.
// ---------------------------------------------------------------------------
__global__ void k_agg(const float* __restrict__ x, double* __restrict__ agg) {
  int idx = blockIdx.x * blockDim.x + threadIdx.x;
  if (idx >= BB * LL) return;
  int b = idx / LL, l = idx - b * LL;
  const float* xb = x + (size_t)b * CC * LL + l;
  float s = 0.0f;
  for (int c = 0; c < CC; c++) s = s + xb[(size_t)c * LL];
  agg[idx] = (double)(s / 64.0f);
}

// ---------------------------------------------------------------------------
// Stage 2: per-window spectral features (32-pt DFT, bins 1..16).
// ---------------------------------------------------------------------------
__global__ void k_winfeat(const double* __restrict__ agg, double* __restrict__ feat) {
  __shared__ double tc[32], tsn[32];
  if (threadIdx.x < 32) {
    double th = 6.283185307179586 * ((double)threadIdx.x / 32.0);
    tc[threadIdx.x] = cos(th);
    tsn[threadIdx.x] = sin(th);
  }
  __syncthreads();
  int idx = blockIdx.x * blockDim.x + threadIdx.x;
  if (idx >= BB * NW) return;
  int b = idx / NW, w = idx - b * NW;
  const double* a = agg + (size_t)b * LL + (size_t)w * 8;
  double av[32];
#pragma unroll
  for (int t = 0; t < 32; t++) av[t] = a[t];
  double p[16];
  for (int k = 1; k <= 16; k++) {
    double re = 0.0, im = 0.0;
    int m = 0;
    for (int t = 0; t < 32; t++) {
      re = re + av[t] * tc[m];
      im = im + av[t] * tsn[m];
      m = (m + k) & 31;
    }
    p[k - 1] = re * re + im * im;
  }
  double r[8];
  for (int i = 0; i < 8; i++) r[i] = p[i] + p[i + 8];
  double sum = ((r[0] + r[1]) + (r[2] + r[3])) + ((r[4] + r[5]) + (r[6] + r[7]));
  double tot = (sum > 1e-8) ? sum : 1e-8;
  double pf[16];
  for (int i = 0; i < 16; i++) pf[i] = p[i] * (double)(i + 1);
  for (int i = 0; i < 8; i++) r[i] = pf[i] + pf[i + 8];
  double spf = ((r[0] + r[1]) + (r[2] + r[3])) + ((r[4] + r[5]) + (r[6] + r[7]));
  int dom = 0;
  double bv = p[0];
  for (int i = 1; i < 16; i++)
    if (p[i] > bv) { bv = p[i]; dom = i; }
  dom += 1;
  double cent = spf / tot;
  double q[16];
  for (int i = 0; i < 16; i++) {
    double d = (double)(i + 1) - cent;
    double dd = d * d;
    q[i] = dd * p[i];
  }
  for (int i = 0; i < 8; i++) r[i] = q[i] + q[i + 8];
  double sv = ((r[0] + r[1]) + (r[2] + r[3])) + ((r[4] + r[5]) + (r[6] + r[7]));
  double var = sv / tot;
  double bw = sqrt(var > 0.0 ? var : 0.0) / 32.0;
  double mean = sum / 16.0;
  double* f = feat + ((size_t)b * NW + (size_t)w) * 3;
  f[0] = (double)dom / 32.0;
  f[1] = bw;
  f[2] = log1p(mean);
}

// ---------------------------------------------------------------------------
// Stage 3: PELT DP. 256 threads (4 waves) per batch; dp in LDS; per-end
// lex-min argmin: ascending per-lane scan (strict <) -> wave butterfly ->
// wave-order combine. Backtrack + boundary filter + segment extraction on
// thread 0.
// ---------------------------------------------------------------------------
__global__ __launch_bounds__(256) void k_dp(const double* __restrict__ feat,
                                            int* __restrict__ bnd_g,
                                            int* __restrict__ nbnd_g,
                                            int* __restrict__ seg_s,
                                            int* __restrict__ seg_e,
                                            int* __restrict__ nseg_g) {
  __shared__ double preL[(NW + 1) * 3];
  __shared__ double pre2L[(NW + 1) * 3];
  __shared__ double dpL[NW + 1];
  __shared__ int prevL[NW + 1];
  __shared__ double pvals[4];
  __shared__ int pidx[4];
  int b = blockIdx.x;
  int tid = threadIdx.x;
  const double* fb = feat + (size_t)b * NW * 3;
  if (tid == 0) {
    double c0 = 0, c1 = 0, c2 = 0, d0 = 0, d1 = 0, d2 = 0;
    preL[0] = 0; preL[1] = 0; preL[2] = 0;
    pre2L[0] = 0; pre2L[1] = 0; pre2L[2] = 0;
    for (int i = 0; i < NW; i++) {
      double f0 = fb[i * 3 + 0], f1 = fb[i * 3 + 1], f2 = fb[i * 3 + 2];
      c0 = c0 + f0; c1 = c1 + f1; c2 = c2 + f2;
      double s0 = f0 * f0, s1 = f1 * f1, s2 = f2 * f2;
      d0 = d0 + s0; d1 = d1 + s1; d2 = d2 + s2;
      preL[(i + 1) * 3 + 0] = c0; preL[(i + 1) * 3 + 1] = c1; preL[(i + 1) * 3 + 2] = c2;
      pre2L[(i + 1) * 3 + 0] = d0; pre2L[(i + 1) * 3 + 1] = d1; pre2L[(i + 1) * 3 + 2] = d2;
    }
    dpL[0] = -1.0;
  }
  __syncthreads();
  int lane = tid & 63, wid = tid >> 6;
  for (int end = 1; end <= NW; end++) {
    double pe0 = preL[end * 3 + 0], pe1 = preL[end * 3 + 1], pe2 = preL[end * 3 + 2];
    double qe0 = pre2L[end * 3 + 0], qe1 = pre2L[end * 3 + 1], qe2 = pre2L[end * 3 + 2];
    double v = __builtin_inf();
    int ix = tid;
    for (int j = tid; j < end; j += 256) {
      double sl = (double)(end - j);
      double s0 = pe0 - preL[j * 3 + 0];
      double s1 = pe1 - preL[j * 3 + 1];
      double s2 = pe2 - preL[j * 3 + 2];
      double u0 = s0 * s0, u1 = s1 * s1, u2 = s2 * s2;
      double t0 = (qe0 - pre2L[j * 3 + 0]) - u0 / sl;
      double t1 = (qe1 - pre2L[j * 3 + 1]) - u1 / sl;
      double t2 = (qe2 - pre2L[j * 3 + 2]) - u2 / sl;
      double sse = (t0 + t1) + t2;
      double cand = (dpL[j] + sse) + 1.0;
      if (cand < v) { v = cand; ix = j; }   // ascending scan: first-occurrence
    }
#pragma unroll
    for (int o = 32; o > 0; o >>= 1) {
      double ov = __shfl_xor(v, o, 64);
      int oi = __shfl_xor(ix, o, 64);
      if (ov < v || (ov == v && oi < ix)) { v = ov; ix = oi; }
    }
    if (lane == 0) { pvals[wid] = v; pidx[wid] = ix; }
    __syncthreads();
    if (tid == 0) {
      double mv = pvals[0];
      int mi = pidx[0];
      for (int t = 1; t < 4; t++) {
        if (pvals[t] < mv || (pvals[t] == mv && pidx[t] < mi)) { mv = pvals[t]; mi = pidx[t]; }
      }
      dpL[end] = mv;
      prevL[end] = mi;
    }
    __syncthreads();
  }
  if (tid == 0) {
    int* chain = (int*)preL;  // reuse LDS
    int cnt = 0, i = NW;
    while (i > 0) { i = prevL[i]; chain[cnt++] = i; }
    int* bbL = (int*)pre2L;   // reuse LDS
    int nb = 0;
    bbL[nb++] = 0;
    for (int t = cnt - 2; t >= 0; t--) {  // interior breakpoints, ascending
      int w = chain[t];
      int tt = w * 8;
      if (tt <= bbL[nb - 1]) continue;
      if (tt - bbL[nb - 1] < 8) continue;
      if (LL - tt < 8) continue;
      bbL[nb++] = tt;
    }
    bbL[nb++] = LL;
    int* bb = bnd_g + (size_t)b * BNDCAP;
    for (int t = 0; t < nb; t++) bb[t] = bbL[t];
    nbnd_g[b] = nb;
    int nseg = nb - 1;
    nseg_g[b] = nseg;
    for (int si = 0; si < nseg; si++) {
      seg_s[(size_t)b * MAXSEG + si] = bbL[si];
      seg_e[(size_t)b * MAXSEG + si] = bbL[si + 1];
    }
  }
}

// ---------------------------------------------------------------------------
// Stage 4a: twiddle tables, flat per batch. Position l in segment [s,e):
// tbl[b*L + l] = cos/sin(2*pi*(l-s)/(e-s)). Segment found by binary search.
// ---------------------------------------------------------------------------
__global__ __launch_bounds__(1024) void k_twiddle(const int* __restrict__ bnd_g,
                                                  const int* __restrict__ nbnd_g,
                                                  double* __restrict__ tblc,
                                                  double* __restrict__ tbls) {
  __shared__ int bbS[BNDCAP];
  int b = blockIdx.x;
  int nb = nbnd_g[b];
  for (int i = threadIdx.x; i < nb; i += 1024) bbS[i] = bnd_g[(size_t)b * BNDCAP + i];
  __syncthreads();
  for (int l = threadIdx.x; l < LL; l += 1024) {
    int lo = 0, hi = nb - 1;
    while (hi - lo > 1) {
      int mid = (lo + hi) >> 1;
      if (bbS[mid] <= l) lo = mid; else hi = mid;
    }
    int s = bbS[lo], e = bbS[lo + 1];
    int n = e - s, m = l - s;
    double th = 6.283185307179586 * ((double)m / (double)n);
    tblc[(size_t)b * LL + l] = cos(th);
    tbls[(size_t)b * LL + l] = sin(th);
  }
}

// ---------------------------------------------------------------------------
// Stage 4b: all DFT bins of all segments in parallel. Bin space per batch is
// flat: segment [s,e) owns bins [s/2, e/2), k = g - s/2 + 1. Inner loop is
// bit-identical to the previous (passing) version's per-bin sum.
// ---------------------------------------------------------------------------
__global__ __launch_bounds__(256) void k_bins(const double* __restrict__ agg,
                                              const int* __restrict__ bnd_g,
                                              const int* __restrict__ nbnd_g,
                                              const double* __restrict__ tblc,
                                              const double* __restrict__ tbls,
                                              double* __restrict__ segp) {
  __shared__ int bbS[BNDCAP];
  int b = blockIdx.y;
  int nb = nbnd_g[b];
  for (int i = threadIdx.x; i < nb; i += 256) bbS[i] = bnd_g[(size_t)b * BNDCAP + i];
  __syncthreads();
  int g = blockIdx.x * 256 + threadIdx.x;  // 0..4095
  int pos = g * 2;
  int lo = 0, hi = nb - 1;
  while (hi - lo > 1) {
    int mid = (lo + hi) >> 1;
    if (bbS[mid] <= pos) lo = mid; else hi = mid;
  }
  int s = bbS[lo], e = bbS[lo + 1];
  int n = e - s;
  int k = g - s / 2 + 1;  // 1..n/2
  const double* tc = tblc + (size_t)b * LL + s;
  const double* tsn = tbls + (size_t)b * LL + s;
  const double* ab = agg + (size_t)b * LL + s;
  double re = 0.0, im = 0.0;
  int m = 0;
#pragma unroll 4
  for (int j = 0; j < n; j++) {
    double av = ab[j];
    re = re + av * tc[m];
    im = im + av * tsn[m];
    m += k;
    if (m >= n) m -= n;
  }
  segp[(size_t)b * NBINS + g] = re * re + im * im;
}

// ---------------------------------------------------------------------------
// Stage 4c: per-segment stats from the flat power rows (staged in LDS),
// one thread per segment. Summation orders identical to reference replica.
// ---------------------------------------------------------------------------
__global__ __launch_bounds__(256) void k_segfin(
    const double* __restrict__ segp, const int* __restrict__ seg_s,
    const int* __restrict__ seg_e, const int* __restrict__ nseg_g,
    int* __restrict__ seg_pl, double* __restrict__ seg_domp,
    double* __restrict__ seg_bw) {
  __shared__ double ppS[NBINS];  // 32 KB
  int b = blockIdx.x;
  for (int i = threadIdx.x; i < NBINS; i += 256) ppS[i] = segp[(size_t)b * NBINS + i];
  __syncthreads();
  int ns = nseg_g[b];
  for (int si = threadIdx.x; si < ns; si += 256) {
    int s = seg_s[(size_t)b * MAXSEG + si];
    int e = seg_e[(size_t)b * MAXSEG + si];
    int n = e - s;
    int nb2 = n / 2;
    int base = s / 2;
    double domp, bwv;
    if (n < 2) {
      domp = 1.0; bwv = 0.0;
    } else if (nb2 <= 1) {
      domp = (double)n; bwv = 0.0;
    } else {
      const double* pp = ppS + base;
      double sum = np_pairwise([&](int i) { return pp[i]; }, 0, nb2);
      double tot = (sum > 1e-8) ? sum : 1e-8;
      int dom = 0;
      double bv = pp[0];
      for (int i = 1; i < nb2; i++)
        if (pp[i] > bv) { bv = pp[i]; dom = i; }
      dom += 1;
      double spf = np_pairwise([&](int i) { return pp[i] * (double)(i + 1); }, 0, nb2);
      double cent = spf / tot;
      double sv = np_pairwise(
          [&](int i) {
            double d = (double)(i + 1) - cent;
            double dd = d * d;
            return dd * pp[i];
          },
          0, nb2);
      double var = sv / tot;
      bwv = sqrt(var > 0.0 ? var : 0.0) / (double)n;
      domp = (double)n / (double)dom;
    }
    double raw = (1.0 * domp) / (1.0 + 1.0 * bwv);
    int pl = (int)rint(raw / 2.0) * 2;  // Python round = half-to-even
    if (pl < 8) pl = 8;
    if (pl > 64) pl = 64;
    seg_pl[(size_t)b * MAXSEG + si] = pl;
    seg_domp[(size_t)b * MAXSEG + si] = domp;
    seg_bw[(size_t)b * MAXSEG + si] = bwv;
  }
}

// ---------------------------------------------------------------------------
// Stage 5: token enumeration (one thread per batch) + n_tokens output.
// ---------------------------------------------------------------------------
__global__ void k_tokens(const int* __restrict__ seg_s, const int* __restrict__ seg_e,
                         const int* __restrict__ seg_pl, const int* __restrict__ nseg_g,
                         int* __restrict__ tok_a, int* __restrict__ tok_z,
                         int* __restrict__ tok_sg, int* __restrict__ ntok_g,
                         float* __restrict__ out_nt) {
  int b = blockIdx.x * blockDim.x + threadIdx.x;
  if (b >= BB) return;
  int ns = nseg_g[b];
  int cnt = 0;
  for (int si = 0; si < ns; si++) {
    int s = seg_s[(size_t)b * MAXSEG + si];
    int e = seg_e[(size_t)b * MAXSEG + si];
    int pl = seg_pl[(size_t)b * MAXSEG + si];
    for (int a = s; a < e; a += pl) {
      int z = a + pl;
      if (z > e) z = e;
      tok_a[(size_t)b * MAXTOK + cnt] = a;
      tok_z[(size_t)b * MAXTOK + cnt] = z;
      tok_sg[(size_t)b * MAXTOK + cnt] = si;
      cnt++;
    }
  }
  ntok_g[b] = cnt;
  out_nt[b] = (float)cnt;
}

// ---------------------------------------------------------------------------
// Stage 6: per-token metadata outputs.
// ---------------------------------------------------------------------------
__global__ void k_tokfill(const int* __restrict__ tok_a, const int* __restrict__ tok_z,
                          const int* __restrict__ tok_sg, const int* __restrict__ ntok_g,
                          const int* __restrict__ seg_s, const int* __restrict__ seg_e,
                          const double* __restrict__ seg_domp,
                          const double* __restrict__ seg_bw, float* __restrict__ out,
                          int mx) {
  int b = blockIdx.x;
  int t = blockIdx.y * blockDim.x + threadIdx.x;
  if (t >= mx) return;
  if (t >= ntok_g[b]) return;
  size_t BM = (size_t)BB * (size_t)mx;
  float* mask = out + BM * 1024;
  float* start = mask + BM;
  float* endo = start + BM;
  float* cen = endo + BM;
  float* span = cen + BM;
  float* reg = span + BM;
  int a = tok_a[(size_t)b * MAXTOK + t];
  int z = tok_z[(size_t)b * MAXTOK + t];
  int si = tok_sg[(size_t)b * MAXTOK + t];
  size_t o = (size_t)b * (size_t)mx + t;
  mask[o] = 1.0f;
  start[o] = (float)a;
  endo[o] = (float)z;
  cen[o] = (float)(((double)(a + z - 1) * 0.5) / 8191.0);
  span[o] = (float)((double)(z - a) / 8192.0);
  int s = seg_s[(size_t)b * MAXSEG + si];
  int e = seg_e[(size_t)b * MAXSEG + si];
  reg[o * 3 + 0] = (float)(seg_domp[(size_t)b * MAXSEG + si] / 8192.0);
  reg[o * 3 + 1] = (float)seg_bw[(size_t)b * MAXSEG + si];
  reg[o * 3 + 2] = (float)((double)(e - s) / 8192.0);
}

// ---------------------------------------------------------------------------
// Stage 7: patch gather.
// ---------------------------------------------------------------------------
__global__ __launch_bounds__(256) void k_patches(const float* __restrict__ x,
                                                 const int* __restrict__ tok_a,
                                                 const int* __restrict__ tok_z,
                                                 const int* __restrict__ ntok_g,
                                                 float* __restrict__ out, int mx) {
  int t = blockIdx.x, b = blockIdx.y;
  if (t >= ntok_g[b]) return;
  __shared__ int g0[16], g1[16];
  __shared__ float wS[16];
  if (threadIdx.x < 16) {
    int a = tok_a[(size_t)b * MAXTOK + t];
    int z = tok_z[(size_t)b * MAXTOK + t];
    int n = z - a;
    double src = ((double)threadIdx.x + 0.5) * ((double)n / 16.0) - 0.5;
    if (src < 0.0) src = 0.0;
    double hi = (double)n - 1.0;
    if (src > hi) src = hi;
    double fi = floor(src);
    int i0 = (int)fi;
    int i1 = i0 + 1;
    if (i1 > n - 1) i1 = n - 1;
    g0[threadIdx.x] = a + i0;
    g1[threadIdx.x] = a + i1;
    wS[threadIdx.x] = (float)(src - fi);
  }
  __syncthreads();
  const float* xb = x + (size_t)b * CC * LL;
  float* ob = out + (((size_t)b * (size_t)mx + t) * CC) * 16;
  for (int e2 = threadIdx.x; e2 < CC * 16; e2 += 256) {
    int c = e2 >> 4, ai = e2 & 15;
    float wv = wS[ai];
    float v0 = xb[(size_t)c * LL + g0[ai]];
    float v1 = xb[(size_t)c * LL + g1[ai]];
    ob[e2] = v0 * (1.0f - wv) + v1 * wv;
  }
}

extern "C" void kernel_launch(void* const* d_in, const int* in_sizes, int n_in,
                              void* d_out, int out_size, void* d_ws, size_t ws_size,
                              hipStream_t stream) {
  (void)in_sizes; (void)n_in; (void)ws_size;
  const float* x = (const float*)d_in[0];
  float* out = (float*)d_out;
  // out_size = B*(1032*mx + 1)  -> recover mx
  long mx = ((long)out_size / BB - 1) / 1032;
  if (mx < 1) mx = 1;

  char* wp = (char*)d_ws;
  size_t off = 0;
  auto carve = [&](size_t bytes) -> void* {
    void* p = wp + off;
    off += (bytes + 255) & ~(size_t)255;
    return p;
  };
  double* agg = (double*)carve((size_t)BB * LL * 8);
  double* feat = (double*)carve((size_t)BB * NW * 3 * 8);
  double* tblc = (double*)carve((size_t)BB * LL * 8);
  double* tbls = (double*)carve((size_t)BB * LL * 8);
  double* segp = (double*)carve((size_t)BB * NBINS * 8);
  double* seg_domp = (double*)carve((size_t)BB * MAXSEG * 8);
  double* seg_bw = (double*)carve((size_t)BB * MAXSEG * 8);
  int* bnd = (int*)carve((size_t)BB * BNDCAP * 4);
  int* nbnd = (int*)carve((size_t)BB * 4);
  int* seg_s = (int*)carve((size_t)BB * MAXSEG * 4);
  int* seg_e = (int*)carve((size_t)BB * MAXSEG * 4);
  int* seg_pl = (int*)carve((size_t)BB * MAXSEG * 4);
  int* nseg = (int*)carve((size_t)BB * 4);
  int* tok_a = (int*)carve((size_t)BB * MAXTOK * 4);
  int* tok_z = (int*)carve((size_t)BB * MAXTOK * 4);
  int* tok_sg = (int*)carve((size_t)BB * MAXTOK * 4);
  int* ntok = (int*)carve((size_t)BB * 4);

  hipMemsetAsync(d_out, 0, (size_t)out_size * sizeof(float), stream);

  k_agg<<<(BB * LL + 255) / 256, 256, 0, stream>>>(x, agg);
  k_winfeat<<<(BB * NW + 255) / 256, 256, 0, stream>>>(agg, feat);
  k_dp<<<BB, 256, 0, stream>>>(feat, bnd, nbnd, seg_s, seg_e, nseg);
  k_twiddle<<<BB, 1024, 0, stream>>>(bnd, nbnd, tblc, tbls);
  dim3 gb(NBINS / 256, BB);
  k_bins<<<gb, 256, 0, stream>>>(agg, bnd, nbnd, tblc, tbls, segp);
  k_segfin<<<BB, 256, 0, stream>>>(segp, seg_s, seg_e, nseg, seg_pl, seg_domp,
                                   seg_bw);
  k_tokens<<<1, 64, 0, stream>>>(seg_s, seg_e, seg_pl, nseg, tok_a, tok_z,
                                 tok_sg, ntok, out + (size_t)BB * (size_t)mx * 1032);
  dim3 gf(BB, (unsigned)((mx + 255) / 256));
  k_tokfill<<<gf, 256, 0, stream>>>(tok_a, tok_z, tok_sg, ntok, seg_s, seg_e,
                                    seg_domp, seg_bw, out, (int)mx);
  dim3 gp((unsigned)mx, BB);
  k_patches<<<gp, 256, 0, stream>>>(x, tok_a, tok_z, ntok, out, (int)mx);
}

// Round 3
// 2691.902 us; speedup vs baseline: 10.5764x; 3.3869x over previous
//
#include <hip/hip_runtime.h>
#include <math.h>

#pragma clang fp contract(off)

#define BB 32
#define CC 64
#define LL 8192
#define NW 1021      // number of spectral windows: (8192-32)/8 + 1
#define MAXSEG 1024
#define MAXTOK 1024
#define BNDCAP 1026
#define NBINS (LL / 2)   // 4096 flat bins per batch (segments partition [0,L))

// ---------------------------------------------------------------------------
// numpy pairwise_sum replica (loops.c.src): n<8 sequential, n<=128 blocked with
// 8 accumulators, else recursive halving with n2 -= n2 % 8.
// ---------------------------------------------------------------------------
template <typename F>
__device__ double np_pairwise(const F& f, int off, int n) {
  if (n < 8) {
    double res = 0.0;
    for (int i = 0; i < n; i++) res = res + f(off + i);
    return res;
  }
  if (n <= 128) {
    double r0 = f(off + 0), r1 = f(off + 1), r2 = f(off + 2), r3 = f(off + 3);
    double r4 = f(off + 4), r5 = f(off + 5), r6 = f(off + 6), r7 = f(off + 7);
    int i = 8;
    int lim = n - (n % 8);
    for (; i < lim; i += 8) {
      r0 = r0 + f(off + i + 0); r1 = r1 + f(off + i + 1);
      r2 = r2 + f(off + i + 2); r3 = r3 + f(off + i + 3);
      r4 = r4 + f(off + i + 4); r5 = r5 + f(off + i + 5);
      r6 = r6 + f(off + i + 6); r7 = r7 + f(off + i + 7);
    }
    double res = ((r0 + r1) + (r2 + r3)) + ((r4 + r5) + (r6 + r7));
    for (; i < n; i++) res = res + f(off + i);
    return res;
  }
  int n2 = n / 2;
  n2 -= n2 % 8;
  return np_pairwise(f, off, n2) + np_pairwise(f, off + n2, n - n2);
}

// ---------------------------------------------------------------------------
// Stage 1: agg[b][l] = channel mean, numpy sequential f32 order.
// ---------------------------------------------------------------------------
__global__ void k_agg(const float* __restrict__ x, double* __restrict__ agg) {
  int idx = blockIdx.x * blockDim.x + threadIdx.x;
  if (idx >= BB * LL) return;
  int b = idx / LL, l = idx - b * LL;
  const float* xb = x + (size_t)b * CC * LL + l;
  float s = 0.0f;
  for (int c = 0; c < CC; c++) s = s + xb[(size_t)c * LL];
  agg[idx] = (double)(s / 64.0f);
}

// ---------------------------------------------------------------------------
// Stage 2: per-window spectral features (32-pt DFT, bins 1..16).
// ---------------------------------------------------------------------------
__global__ void k_winfeat(const double* __restrict__ agg, double* __restrict__ feat) {
  __shared__ double tc[32], tsn[32];
  if (threadIdx.x < 32) {
    double th = 6.283185307179586 * ((double)threadIdx.x / 32.0);
    tc[threadIdx.x] = cos(th);
    tsn[threadIdx.x] = sin(th);
  }
  __syncthreads();
  int idx = blockIdx.x * blockDim.x + threadIdx.x;
  if (idx >= BB * NW) return;
  int b = idx / NW, w = idx - b * NW;
  const double* a = agg + (size_t)b * LL + (size_t)w * 8;
  double av[32];
#pragma unroll
  for (int t = 0; t < 32; t++) av[t] = a[t];
  double p[16];
  for (int k = 1; k <= 16; k++) {
    double re = 0.0, im = 0.0;
    int m = 0;
    for (int t = 0; t < 32; t++) {
      re = re + av[t] * tc[m];
      im = im + av[t] * tsn[m];
      m = (m + k) & 31;
    }
    p[k - 1] = re * re + im * im;
  }
  double r[8];
  for (int i = 0; i < 8; i++) r[i] = p[i] + p[i + 8];
  double sum = ((r[0] + r[1]) + (r[2] + r[3])) + ((r[4] + r[5]) + (r[6] + r[7]));
  double tot = (sum > 1e-8) ? sum : 1e-8;
  double pf[16];
  for (int i = 0; i < 16; i++) pf[i] = p[i] * (double)(i + 1);
  for (int i = 0; i < 8; i++) r[i] = pf[i] + pf[i + 8];
  double spf = ((r[0] + r[1]) + (r[2] + r[3])) + ((r[4] + r[5]) + (r[6] + r[7]));
  int dom = 0;
  double bv = p[0];
  for (int i = 1; i < 16; i++)
    if (p[i] > bv) { bv = p[i]; dom = i; }
  dom += 1;
  double cent = spf / tot;
  double q[16];
  for (int i = 0; i < 16; i++) {
    double d = (double)(i + 1) - cent;
    double dd = d * d;
    q[i] = dd * p[i];
  }
  for (int i = 0; i < 8; i++) r[i] = q[i] + q[i + 8];
  double sv = ((r[0] + r[1]) + (r[2] + r[3])) + ((r[4] + r[5]) + (r[6] + r[7]));
  double var = sv / tot;
  double bw = sqrt(var > 0.0 ? var : 0.0) / 32.0;
  double mean = sum / 16.0;
  double* f = feat + ((size_t)b * NW + (size_t)w) * 3;
  f[0] = (double)dom / 32.0;
  f[1] = bw;
  f[2] = log1p(mean);
}

// ---------------------------------------------------------------------------
// Stage 3: PELT DP. 256 threads (4 waves) per batch.
// ---------------------------------------------------------------------------
__global__ __launch_bounds__(256) void k_dp(const double* __restrict__ feat,
                                            int* __restrict__ bnd_g,
                                            int* __restrict__ nbnd_g,
                                            int* __restrict__ seg_s,
                                            int* __restrict__ seg_e,
                                            int* __restrict__ nseg_g) {
  __shared__ double preL[(NW + 1) * 3];
  __shared__ double pre2L[(NW + 1) * 3];
  __shared__ double dpL[NW + 1];
  __shared__ int prevL[NW + 1];
  __shared__ double pvals[4];
  __shared__ int pidx[4];
  int b = blockIdx.x;
  int tid = threadIdx.x;
  const double* fb = feat + (size_t)b * NW * 3;
  if (tid == 0) {
    double c0 = 0, c1 = 0, c2 = 0, d0 = 0, d1 = 0, d2 = 0;
    preL[0] = 0; preL[1] = 0; preL[2] = 0;
    pre2L[0] = 0; pre2L[1] = 0; pre2L[2] = 0;
    for (int i = 0; i < NW; i++) {
      double f0 = fb[i * 3 + 0], f1 = fb[i * 3 + 1], f2 = fb[i * 3 + 2];
      c0 = c0 + f0; c1 = c1 + f1; c2 = c2 + f2;
      double s0 = f0 * f0, s1 = f1 * f1, s2 = f2 * f2;
      d0 = d0 + s0; d1 = d1 + s1; d2 = d2 + s2;
      preL[(i + 1) * 3 + 0] = c0; preL[(i + 1) * 3 + 1] = c1; preL[(i + 1) * 3 + 2] = c2;
      pre2L[(i + 1) * 3 + 0] = d0; pre2L[(i + 1) * 3 + 1] = d1; pre2L[(i + 1) * 3 + 2] = d2;
    }
    dpL[0] = -1.0;
  }
  __syncthreads();
  int lane = tid & 63, wid = tid >> 6;
  for (int end = 1; end <= NW; end++) {
    double pe0 = preL[end * 3 + 0], pe1 = preL[end * 3 + 1], pe2 = preL[end * 3 + 2];
    double qe0 = pre2L[end * 3 + 0], qe1 = pre2L[end * 3 + 1], qe2 = pre2L[end * 3 + 2];
    double v = __builtin_inf();
    int ix = tid;
    for (int j = tid; j < end; j += 256) {
      double sl = (double)(end - j);
      double s0 = pe0 - preL[j * 3 + 0];
      double s1 = pe1 - preL[j * 3 + 1];
      double s2 = pe2 - preL[j * 3 + 2];
      double u0 = s0 * s0, u1 = s1 * s1, u2 = s2 * s2;
      double t0 = (qe0 - pre2L[j * 3 + 0]) - u0 / sl;
      double t1 = (qe1 - pre2L[j * 3 + 1]) - u1 / sl;
      double t2 = (qe2 - pre2L[j * 3 + 2]) - u2 / sl;
      double sse = (t0 + t1) + t2;
      double cand = (dpL[j] + sse) + 1.0;
      if (cand < v) { v = cand; ix = j; }   // ascending scan: first-occurrence
    }
#pragma unroll
    for (int o = 32; o > 0; o >>= 1) {
      double ov = __shfl_xor(v, o, 64);
      int oi = __shfl_xor(ix, o, 64);
      if (ov < v || (ov == v && oi < ix)) { v = ov; ix = oi; }
    }
    if (lane == 0) { pvals[wid] = v; pidx[wid] = ix; }
    __syncthreads();
    if (tid == 0) {
      double mv = pvals[0];
      int mi = pidx[0];
      for (int t = 1; t < 4; t++) {
        if (pvals[t] < mv || (pvals[t] == mv && pidx[t] < mi)) { mv = pvals[t]; mi = pidx[t]; }
      }
      dpL[end] = mv;
      prevL[end] = mi;
    }
    __syncthreads();
  }
  if (tid == 0) {
    int* chain = (int*)preL;  // reuse LDS
    int cnt = 0, i = NW;
    while (i > 0) { i = prevL[i]; chain[cnt++] = i; }
    int* bbL = (int*)pre2L;   // reuse LDS
    int nb = 0;
    bbL[nb++] = 0;
    for (int t = cnt - 2; t >= 0; t--) {  // interior breakpoints, ascending
      int w = chain[t];
      int tt = w * 8;
      if (tt <= bbL[nb - 1]) continue;
      if (tt - bbL[nb - 1] < 8) continue;
      if (LL - tt < 8) continue;
      bbL[nb++] = tt;
    }
    bbL[nb++] = LL;
    int* bb = bnd_g + (size_t)b * BNDCAP;
    for (int t = 0; t < nb; t++) bb[t] = bbL[t];
    nbnd_g[b] = nb;
    int nseg = nb - 1;
    nseg_g[b] = nseg;
    for (int si = 0; si < nseg; si++) {
      seg_s[(size_t)b * MAXSEG + si] = bbL[si];
      seg_e[(size_t)b * MAXSEG + si] = bbL[si + 1];
    }
  }
}

// ---------------------------------------------------------------------------
// Stage 4: all DFT bins of all segments in parallel, table-free.
// Segment [s,e) owns flat bins [s/2, e/2), k = g - s/2 + 1. Twiddles advance
// by an in-register complex rotation along 4 interleaved j-chains (n is a
// multiple of 8). No scattered loads: agg[j] is wave-uniform (broadcast).
// fp contraction allowed here: only power magnitudes feed robust decisions.
// ---------------------------------------------------------------------------
__global__ __launch_bounds__(256) void k_bins(const double* __restrict__ agg,
                                              const int* __restrict__ bnd_g,
                                              const int* __restrict__ nbnd_g,
                                              double* __restrict__ segp) {
#pragma clang fp contract(fast)
  __shared__ int bbS[BNDCAP];
  int b = blockIdx.y;
  int nb = nbnd_g[b];
  for (int i = threadIdx.x; i < nb; i += 256) bbS[i] = bnd_g[(size_t)b * BNDCAP + i];
  __syncthreads();
  int g = blockIdx.x * 256 + threadIdx.x;  // 0..4095
  int pos = g * 2;
  int lo = 0, hi = nb - 1;
  while (hi - lo > 1) {
    int mid = (lo + hi) >> 1;
    if (bbS[mid] <= pos) lo = mid; else hi = mid;
  }
  int s = bbS[lo], e = bbS[lo + 1];
  int n = e - s;
  int k = g - s / 2 + 1;  // 1..n/2
  const double* ab = agg + (size_t)b * LL + s;
  const double twopi = 6.283185307179586;
  // step rotation for stride-4 chains
  int m4 = (4 * k) % n;
  double dth = twopi * ((double)m4 / (double)n);
  double cd = cos(dth), sd = sin(dth);
  // chain starts at j0 = 0..3: theta = 2*pi*((j0*k) mod n)/n
  double c0, s0c, c1, s1c, c2, s2c, c3, s3c;
  {
    int m1 = k % n, m2 = (2 * k) % n, m3 = (3 * k) % n;
    c0 = 1.0; s0c = 0.0;
    double t1 = twopi * ((double)m1 / (double)n);
    double t2 = twopi * ((double)m2 / (double)n);
    double t3 = twopi * ((double)m3 / (double)n);
    c1 = cos(t1); s1c = sin(t1);
    c2 = cos(t2); s2c = sin(t2);
    c3 = cos(t3); s3c = sin(t3);
  }
  double re0 = 0, re1 = 0, re2 = 0, re3 = 0;
  double im0 = 0, im1 = 0, im2 = 0, im3 = 0;
  int steps = n >> 2;  // n % 8 == 0 always
  for (int t = 0; t < steps; t++) {
    int j = t << 2;
    double a0 = ab[j + 0], a1 = ab[j + 1], a2 = ab[j + 2], a3 = ab[j + 3];
    re0 = re0 + a0 * c0; im0 = im0 + a0 * s0c;
    re1 = re1 + a1 * c1; im1 = im1 + a1 * s1c;
    re2 = re2 + a2 * c2; im2 = im2 + a2 * s2c;
    re3 = re3 + a3 * c3; im3 = im3 + a3 * s3c;
    double nc0 = c0 * cd - s0c * sd, ns0 = s0c * cd + c0 * sd;
    double nc1 = c1 * cd - s1c * sd, ns1 = s1c * cd + c1 * sd;
    double nc2 = c2 * cd - s2c * sd, ns2 = s2c * cd + c2 * sd;
    double nc3 = c3 * cd - s3c * sd, ns3 = s3c * cd + c3 * sd;
    c0 = nc0; s0c = ns0; c1 = nc1; s1c = ns1;
    c2 = nc2; s2c = ns2; c3 = nc3; s3c = ns3;
  }
  double re = (re0 + re1) + (re2 + re3);
  double im = (im0 + im1) + (im2 + im3);
  segp[(size_t)b * NBINS + g] = re * re + im * im;
}

// ---------------------------------------------------------------------------
// Stage 4c: per-segment stats from the flat power rows (staged in LDS),
// one thread per segment. Summation orders = numpy replica.
// ---------------------------------------------------------------------------
__global__ __launch_bounds__(256) void k_segfin(
    const double* __restrict__ segp, const int* __restrict__ seg_s,
    const int* __restrict__ seg_e, const int* __restrict__ nseg_g,
    int* __restrict__ seg_pl, double* __restrict__ seg_domp,
    double* __restrict__ seg_bw) {
  __shared__ double ppS[NBINS];  // 32 KB
  int b = blockIdx.x;
  for (int i = threadIdx.x; i < NBINS; i += 256) ppS[i] = segp[(size_t)b * NBINS + i];
  __syncthreads();
  int ns = nseg_g[b];
  for (int si = threadIdx.x; si < ns; si += 256) {
    int s = seg_s[(size_t)b * MAXSEG + si];
    int e = seg_e[(size_t)b * MAXSEG + si];
    int n = e - s;
    int nb2 = n / 2;
    int base = s / 2;
    double domp, bwv;
    if (n < 2) {
      domp = 1.0; bwv = 0.0;
    } else if (nb2 <= 1) {
      domp = (double)n; bwv = 0.0;
    } else {
      const double* pp = ppS + base;
      double sum = np_pairwise([&](int i) { return pp[i]; }, 0, nb2);
      double tot = (sum > 1e-8) ? sum : 1e-8;
      int dom = 0;
      double bv = pp[0];
      for (int i = 1; i < nb2; i++)
        if (pp[i] > bv) { bv = pp[i]; dom = i; }
      dom += 1;
      double spf = np_pairwise([&](int i) { return pp[i] * (double)(i + 1); }, 0, nb2);
      double cent = spf / tot;
      double sv = np_pairwise(
          [&](int i) {
            double d = (double)(i + 1) - cent;
            double dd = d * d;
            return dd * pp[i];
          },
          0, nb2);
      double var = sv / tot;
      bwv = sqrt(var > 0.0 ? var : 0.0) / (double)n;
      domp = (double)n / (double)dom;
    }
    double raw = (1.0 * domp) / (1.0 + 1.0 * bwv);
    int pl = (int)rint(raw / 2.0) * 2;  // Python round = half-to-even
    if (pl < 8) pl = 8;
    if (pl > 64) pl = 64;
    seg_pl[(size_t)b * MAXSEG + si] = pl;
    seg_domp[(size_t)b * MAXSEG + si] = domp;
    seg_bw[(size_t)b * MAXSEG + si] = bwv;
  }
}

// ---------------------------------------------------------------------------
// Stage 5: token enumeration (one thread per batch) + n_tokens output.
// ---------------------------------------------------------------------------
__global__ void k_tokens(const int* __restrict__ seg_s, const int* __restrict__ seg_e,
                         const int* __restrict__ seg_pl, const int* __restrict__ nseg_g,
                         int* __restrict__ tok_a, int* __restrict__ tok_z,
                         int* __restrict__ tok_sg, int* __restrict__ ntok_g,
                         float* __restrict__ out_nt) {
  int b = blockIdx.x * blockDim.x + threadIdx.x;
  if (b >= BB) return;
  int ns = nseg_g[b];
  int cnt = 0;
  for (int si = 0; si < ns; si++) {
    int s = seg_s[(size_t)b * MAXSEG + si];
    int e = seg_e[(size_t)b * MAXSEG + si];
    int pl = seg_pl[(size_t)b * MAXSEG + si];
    for (int a = s; a < e; a += pl) {
      int z = a + pl;
      if (z > e) z = e;
      tok_a[(size_t)b * MAXTOK + cnt] = a;
      tok_z[(size_t)b * MAXTOK + cnt] = z;
      tok_sg[(size_t)b * MAXTOK + cnt] = si;
      cnt++;
    }
  }
  ntok_g[b] = cnt;
  out_nt[b] = (float)cnt;
}

// ---------------------------------------------------------------------------
// Stage 6: per-token metadata outputs.
// ---------------------------------------------------------------------------
__global__ void k_tokfill(const int* __restrict__ tok_a, const int* __restrict__ tok_z,
                          const int* __restrict__ tok_sg, const int* __restrict__ ntok_g,
                          const int* __restrict__ seg_s, const int* __restrict__ seg_e,
                          const double* __restrict__ seg_domp,
                          const double* __restrict__ seg_bw, float* __restrict__ out,
                          int mx) {
  int b = blockIdx.x;
  int t = blockIdx.y * blockDim.x + threadIdx.x;
  if (t >= mx) return;
  if (t >= ntok_g[b]) return;
  size_t BM = (size_t)BB * (size_t)mx;
  float* mask = out + BM * 1024;
  float* start = mask + BM;
  float* endo = start + BM;
  float* cen = endo + BM;
  float* span = cen + BM;
  float* reg = span + BM;
  int a = tok_a[(size_t)b * MAXTOK + t];
  int z = tok_z[(size_t)b * MAXTOK + t];
  int si = tok_sg[(size_t)b * MAXTOK + t];
  size_t o = (size_t)b * (size_t)mx + t;
  mask[o] = 1.0f;
  start[o] = (float)a;
  endo[o] = (float)z;
  cen[o] = (float)(((double)(a + z - 1) * 0.5) / 8191.0);
  span[o] = (float)((double)(z - a) / 8192.0);
  int s = seg_s[(size_t)b * MAXSEG + si];
  int e = seg_e[(size_t)b * MAXSEG + si];
  reg[o * 3 + 0] = (float)(seg_domp[(size_t)b * MAXSEG + si] / 8192.0);
  reg[o * 3 + 1] = (float)seg_bw[(size_t)b * MAXSEG + si];
  reg[o * 3 + 2] = (float)((double)(e - s) / 8192.0);
}

// ---------------------------------------------------------------------------
// Stage 7: patch gather.
// ---------------------------------------------------------------------------
__global__ __launch_bounds__(256) void k_patches(const float* __restrict__ x,
                                                 const int* __restrict__ tok_a,
                                                 const int* __restrict__ tok_z,
                                                 const int* __restrict__ ntok_g,
                                                 float* __restrict__ out, int mx) {
  int t = blockIdx.x, b = blockIdx.y;
  if (t >= ntok_g[b]) return;
  __shared__ int g0[16], g1[16];
  __shared__ float wS[16];
  if (threadIdx.x < 16) {
    int a = tok_a[(size_t)b * MAXTOK + t];
    int z = tok_z[(size_t)b * MAXTOK + t];
    int n = z - a;
    double src = ((double)threadIdx.x + 0.5) * ((double)n / 16.0) - 0.5;
    if (src < 0.0) src = 0.0;
    double hi = (double)n - 1.0;
    if (src > hi) src = hi;
    double fi = floor(src);
    int i0 = (int)fi;
    int i1 = i0 + 1;
    if (i1 > n - 1) i1 = n - 1;
    g0[threadIdx.x] = a + i0;
    g1[threadIdx.x] = a + i1;
    wS[threadIdx.x] = (float)(src - fi);
  }
  __syncthreads();
  const float* xb = x + (size_t)b * CC * LL;
  float* ob = out + (((size_t)b * (size_t)mx + t) * CC) * 16;
  for (int e2 = threadIdx.x; e2 < CC * 16; e2 += 256) {
    int c = e2 >> 4, ai = e2 & 15;
    float wv = wS[ai];
    float v0 = xb[(size_t)c * LL + g0[ai]];
    float v1 = xb[(size_t)c * LL + g1[ai]];
    ob[e2] = v0 * (1.0f - wv) + v1 * wv;
  }
}

extern "C" void kernel_launch(void* const* d_in, const int* in_sizes, int n_in,
                              void* d_out, int out_size, void* d_ws, size_t ws_size,
                              hipStream_t stream) {
  (void)in_sizes; (void)n_in; (void)ws_size;
  const float* x = (const float*)d_in[0];
  float* out = (float*)d_out;
  // out_size = B*(1032*mx + 1)  -> recover mx
  long mx = ((long)out_size / BB - 1) / 1032;
  if (mx < 1) mx = 1;

  char* wp = (char*)d_ws;
  size_t off = 0;
  auto carve = [&](size_t bytes) -> void* {
    void* p = wp + off;
    off += (bytes + 255) & ~(size_t)255;
    return p;
  };
  double* agg = (double*)carve((size_t)BB * LL * 8);
  double* feat = (double*)carve((size_t)BB * NW * 3 * 8);
  double* segp = (double*)carve((size_t)BB * NBINS * 8);
  double* seg_domp = (double*)carve((size_t)BB * MAXSEG * 8);
  double* seg_bw = (double*)carve((size_t)BB * MAXSEG * 8);
  int* bnd = (int*)carve((size_t)BB * BNDCAP * 4);
  int* nbnd = (int*)carve((size_t)BB * 4);
  int* seg_s = (int*)carve((size_t)BB * MAXSEG * 4);
  int* seg_e = (int*)carve((size_t)BB * MAXSEG * 4);
  int* seg_pl = (int*)carve((size_t)BB * MAXSEG * 4);
  int* nseg = (int*)carve((size_t)BB * 4);
  int* tok_a = (int*)carve((size_t)BB * MAXTOK * 4);
  int* tok_z = (int*)carve((size_t)BB * MAXTOK * 4);
  int* tok_sg = (int*)carve((size_t)BB * MAXTOK * 4);
  int* ntok = (int*)carve((size_t)BB * 4);

  hipMemsetAsync(d_out, 0, (size_t)out_size * sizeof(float), stream);

  k_agg<<<(BB * LL + 255) / 256, 256, 0, stream>>>(x, agg);
  k_winfeat<<<(BB * NW + 255) / 256, 256, 0, stream>>>(agg, feat);
  k_dp<<<BB, 256, 0, stream>>>(feat, bnd, nbnd, seg_s, seg_e, nseg);
  dim3 gb(NBINS / 256, BB);
  k_bins<<<gb, 256, 0, stream>>>(agg, bnd, nbnd, segp);
  k_segfin<<<BB, 256, 0, stream>>>(segp, seg_s, seg_e, nseg, seg_pl, seg_domp,
                                   seg_bw);
  k_tokens<<<1, 64, 0, stream>>>(seg_s, seg_e, seg_pl, nseg, tok_a, tok_z,
                                 tok_sg, ntok, out + (size_t)BB * (size_t)mx * 1032);
  dim3 gf(BB, (unsigned)((mx + 255) / 256));
  k_tokfill<<<gf, 256, 0, stream>>>(tok_a, tok_z, tok_sg, ntok, seg_s, seg_e,
                                    seg_domp, seg_bw, out, (int)mx);
  dim3 gp((unsigned)mx, BB);
  k_patches<<<gp, 256, 0, stream>>>(x, tok_a, tok_z, ntok, out, (int)mx);
}